// Round 8
// baseline (204.739 us; speedup 1.0000x reference)
//
#include <hip/hip_runtime.h>
#include <hip/hip_bf16.h>
#include <cstdint>
#include <cstddef>

typedef short short8 __attribute__((ext_vector_type(8)));
typedef float f32x4 __attribute__((ext_vector_type(4)));
typedef float f32x2 __attribute__((ext_vector_type(2)));

#define NS    2048
#define KPAD  288
#define H2    512
#define HID   256
#define WPB   7       // windows per sig workgroup (192 thr = 3 waves = 3 thirds)
#define SBLK  293     // ceil(2048/7)

#define MFMA(a,b,c) __builtin_amdgcn_mfma_f32_16x16x32_bf16((a),(b),(c),0,0,0)

__device__ __forceinline__ float geluf(float x) {
    return 0.5f * x * (1.0f + erff(x * 0.70710678118654752f));
}
__device__ __forceinline__ f32x4 shfl4(f32x4 v, int d) {
    f32x4 r;
    r[0] = __shfl_xor(v[0], d); r[1] = __shfl_xor(v[1], d);
    r[2] = __shfl_xor(v[2], d); r[3] = __shfl_xor(v[3], d);
    return r;
}

struct Tbl3 { short col[729]; };
static constexpr Tbl3 make_tbl3() {
    Tbl3 t{};
    for (int x = 0; x < 729; ++x) t.col[x] = -1;
    int r = 0;
    for (int i = 0; i < 9; ++i)
        for (int j = 0; j < 9; ++j)
            for (int k = 0; k < 9; ++k) {
                bool lt1 = (i < j) || (i == j && (j < k || (j == k && k < i)));
                bool lt2 = (i < k) || (i == k && (j < i || (j == i && k < j)));
                if (lt1 && lt2) { t.col[(i*9+j)*9+k] = (short)(45 + r); ++r; }
            }
    return t;
}
static constexpr Tbl3 TBL3 = make_tbl3();

// ============================================================================
// sig kernel: UNCHANGED from round 7 (3 thirds x 1 wave, pk-f32 math,
// zero-padded diff rows).  Will attack next round once counters surface.
// ============================================================================
#define SIG_STEP(VA_,VB_,VC_) { \
    const float hh = 0.5f * S1i + vi * (1.0f/6.0f); \
    const float ra = S2ra + hh * (VA_); \
    const float rb = S2rb + hh * (VB_); \
    const float rc = S2rc + hh * (VC_); \
    const f32x2 ra2 = {ra, ra}, rb2 = {rb, rb}, rc2 = {rc, rc}; \
    S3sa += ra * v0; S3pa0 += ra2*vp0; S3pa1 += ra2*vp1; S3pa2 += ra2*vp2; S3pa3 += ra2*vp3; \
    S3sb += rb * v0; S3pb0 += rb2*vp0; S3pb1 += rb2*vp1; S3pb2 += rb2*vp2; S3pb3 += rb2*vp3; \
    S3sc += rc * v0; S3pc0 += rc2*vp0; S3pc1 += rc2*vp1; S3pc2 += rc2*vp2; S3pc3 += rc2*vp3; \
    const float aa = S1i + 0.5f * vi; \
    S2ra += aa * (VA_); S2rb += aa * (VB_); S2rc += aa * (VC_); \
    S1i += vi; }

#define SIG_MAIN(VA_,VB_,VC_) { \
    { const float* xr = &X[(g0 - lo) * 8]; \
      const float4 e0 = *(const float4*)xr; \
      const float4 e1 = *(const float4*)(xr + 4); \
      const float rs = xr[ioff]; \
      const float v0 = 0.0f; \
      const f32x2 vp0 = {e0.x, e0.y}, vp1 = {e0.z, e0.w}, vp2 = {e1.x, e1.y}, vp3 = {e1.z, e1.w}; \
      const float vi = (ci == 0) ? 0.0f : rs; \
      SIG_STEP(VA_,VB_,VC_) } \
    const float* pd = &PD[(sm59 + 1 - lo + 59) * 8]; \
    float4 d0 = *(const float4*)pd; \
    float4 d1 = *(const float4*)(pd + 4); \
    float rn = pd[ioff]; \
    _Pragma("unroll 2") \
    for (int j = 1; j < 60; ++j) { \
      const float4 e0 = d0; const float4 e1 = d1; const float rs = rn; \
      pd += 8; \
      d0 = *(const float4*)pd; d1 = *(const float4*)(pd + 4); rn = pd[ioff]; \
      const float v0 = DT; \
      const f32x2 vp0 = {e0.x, e0.y}, vp1 = {e0.z, e0.w}, vp2 = {e1.x, e1.y}, vp3 = {e1.z, e1.w}; \
      const float vi = (ci == 0) ? DT : rs; \
      SIG_STEP(VA_,VB_,VC_) \
    } }

#define SIG_ST(RA,RB,RC) \
    if (act) { \
        if ((RA) == 0) S1buf[widx * 9 + ci] = S1i; \
        float* sb = &S2buf[widx * 81 + ci * 9]; \
        sb[RA] = S2ra; sb[RB] = S2rb; sb[RC] = S2rc; \
    }

#define S3EL0(SL) S3s##SL
#define S3EL1(SL) S3p##SL##0[0]
#define S3EL2(SL) S3p##SL##0[1]
#define S3EL3(SL) S3p##SL##1[0]
#define S3EL4(SL) S3p##SL##1[1]
#define S3EL5(SL) S3p##SL##2[0]
#define S3EL6(SL) S3p##SL##2[1]
#define S3EL7(SL) S3p##SL##3[0]
#define S3EL8(SL) S3p##SL##3[1]

#define SIG_E2(SL,J2) if (ci < (J2)) { \
    const float val2 = S2r##SL - 0.5f * S1i * s1v##J2; \
    const int col2 = 9 + ci*8 - (ci*(ci-1))/2 + ((J2) - ci - 1); \
    frow[col2] = __float2bfloat16(val2); }

#define SIG_E3(SL,R,K) { const int col3 = TBL3.col[tb + (R)*9 + (K)]; \
    if (col3 >= 0) { \
        const float val3 = S3EL##K(SL) \
            - 0.5f * (S1i * S2w[(R)*9+(K)] + S2r##SL * s1v##K) \
            + S1i * s1v##R * s1v##K * (1.0f/3.0f); \
        frow[col3] = __float2bfloat16(val3); } }

#define SIG_E3R(SL,R) SIG_E3(SL,R,0) SIG_E3(SL,R,1) SIG_E3(SL,R,2) SIG_E3(SL,R,3) \
    SIG_E3(SL,R,4) SIG_E3(SL,R,5) SIG_E3(SL,R,6) SIG_E3(SL,R,7) SIG_E3(SL,R,8)

#define SIG_EMIT(RA,RB,RC) \
    if (act) { \
        if ((RA) == 0) { \
            frow[ci] = __float2bfloat16(S1i); \
            if (ci == 0) { \
                const __hip_bfloat16 z16 = __float2bfloat16(0.0f); \
                frow[285] = z16; frow[286] = z16; frow[287] = z16; \
            } \
        } \
        SIG_E2(a,RA) SIG_E2(b,RB) SIG_E2(c,RC) \
        SIG_E3R(a,RA) SIG_E3R(b,RB) SIG_E3R(c,RC) \
    }

__global__ __launch_bounds__(192) __attribute__((amdgpu_waves_per_eu(1, 6)))
void sig_kernel(const float* __restrict__ x, __hip_bfloat16* __restrict__ feats) {
    __shared__ __align__(16) float X[66 * 8];
    __shared__ __align__(16) float PD[126 * 8];
    __shared__ float S2buf[WPB * 81];
    __shared__ float S1buf[WPB * 9];

    const int blk = blockIdx.x;
    const int b   = blk / SBLK;
    const int s0  = (blk % SBLK) * WPB;
    const int lo  = (s0 - 59 > 0) ? (s0 - 59) : 0;
    const int hi  = (s0 + WPB - 1 < NS - 1) ? (s0 + WPB - 1) : (NS - 1);
    const int nrow = hi - lo + 1;     // <= 66
    const int tid = threadIdx.x;

    {
        const float4* src = (const float4*)(x + ((size_t)b * NS + lo) * 8);
        float4* X4 = (float4*)X;
        const int n4 = nrow * 2;
        for (int t = tid; t < n4; t += 192) X4[t] = src[t];
    }
    __syncthreads();
    {
        const float4* X4 = (const float4*)X;
        float4* PD4 = (float4*)PD;
        for (int t = tid; t < 252; t += 192) {
            const int p = t >> 1;
            const int r = p - 59;
            float4 dv = {0.f, 0.f, 0.f, 0.f};
            if (r > 0 && r < nrow) {
                const float4 a = X4[t - 118], bb = X4[t - 120];
                dv.x = a.x - bb.x; dv.y = a.y - bb.y; dv.z = a.z - bb.z; dv.w = a.w - bb.w;
            }
            PD4[t] = dv;
        }
    }
    __syncthreads();

    const int t3    = tid >> 6;
    const int lt    = tid & 63;
    const int widx0 = lt / 9;
    const int ci    = lt - widx0 * 9;
    const bool act  = (lt < 63) && (s0 + widx0 < NS);
    const int widx  = (widx0 < WPB - 1) ? widx0 : WPB - 1;
    int s = s0 + widx; if (s > NS - 1) s = NS - 1;

    float S3sa=0.f, S3sb=0.f, S3sc=0.f;
    f32x2 S3pa0={0.f,0.f},S3pa1={0.f,0.f},S3pa2={0.f,0.f},S3pa3={0.f,0.f};
    f32x2 S3pb0={0.f,0.f},S3pb1={0.f,0.f},S3pb2={0.f,0.f},S3pb3={0.f,0.f};
    f32x2 S3pc0={0.f,0.f},S3pc1={0.f,0.f},S3pc2={0.f,0.f},S3pc3={0.f,0.f};
    float S2ra=0.f, S2rb=0.f, S2rc=0.f;
    float S1i = 0.f;
    const int ioff = (ci > 0) ? (ci - 1) : 0;
    const int sm59 = s - 59;
    const int g0   = (sm59 > 0) ? sm59 : 0;
    const float DT = 1.0f / 59.0f;

    if (t3 == 0)      { SIG_MAIN(v0,   e0.x, e0.y) }
    else if (t3 == 1) { SIG_MAIN(e0.z, e0.w, e1.x) }
    else              { SIG_MAIN(e1.y, e1.z, e1.w) }

    if (t3 == 0)      { SIG_ST(0,1,2) }
    else if (t3 == 1) { SIG_ST(3,4,5) }
    else              { SIG_ST(6,7,8) }
    __syncthreads();

    const float* s1p = &S1buf[widx * 9];
    const float s1v0=s1p[0], s1v1=s1p[1], s1v2=s1p[2], s1v3=s1p[3], s1v4=s1p[4];
    const float s1v5=s1p[5], s1v6=s1p[6], s1v7=s1p[7], s1v8=s1p[8];
    const float* S2w = &S2buf[widx * 81];
    const int tb = ci * 81;
    __hip_bfloat16* frow = feats + (size_t)(b * NS + s) * KPAD;

    if (t3 == 0)      { SIG_EMIT(0,1,2) }
    else if (t3 == 1) { SIG_EMIT(3,4,5) }
    else              { SIG_EMIT(6,7,8) }
}

// ============================================================================
// Weight prep: w1T[512][288] bf16, w2T[256][512] bf16 ([n][k] layouts)
// ============================================================================
__global__ void convert_w1(const float* __restrict__ w1, __hip_bfloat16* __restrict__ w1T) {
    const int n = blockIdx.x;          // 0..511
    const int k = threadIdx.x;         // 0..287
    const float v = (k < 285) ? w1[(size_t)k * H2 + n] : 0.0f;
    w1T[(size_t)n * KPAD + k] = __float2bfloat16(v);
}
__global__ void convert_w2(const float* __restrict__ w2, __hip_bfloat16* __restrict__ w2T) {
    const int n = blockIdx.x;          // 0..255
    const int k = threadIdx.x;         // 0..511
    w2T[(size_t)n * H2 + k] = __float2bfloat16(w2[(size_t)k * HID + n]);
}

#define REP16(M) M(0) M(1) M(2) M(3) M(4) M(5) M(6) M(7) M(8) M(9) M(10) M(11) M(12) M(13) M(14) M(15)
#define REP8(M)  M(0) M(1) M(2) M(3) M(4) M(5) M(6) M(7)

// ============================================================================
// GEMM1 (direct-load, NO LDS staging, NO K-loop barriers):
// block = 64 rows x 512 cols, 512 thr = 8 waves as 4(M) x 2(N-half).
// Every fragment is a global_load_dwordx4 straight from L2/L3; fused
// bias + exact GELU + in-block LayerNorm -> bf16 h1.
// r7 lesson: the 2-barrier vmcnt(0) K-loop at 9 iterations ran at 73 TF
// (MfmaUtil 2.7%) — the drain can never amortize at this K.
// ============================================================================
#define G1_DECL(nf) f32x4 acc##nf = {0.f,0.f,0.f,0.f};
#define G1_LD(nf)   const short8 bv##nf = *(const short8*)(brow + (nf)*16*KPAD + ko);
#define G1_FM(nf)   acc##nf = MFMA(av, bv##nf, acc##nf);
#define G1_BIAS(nf) const float bias##nf = b1[wc*256 + (nf)*16 + l16];
#define G1_GELU(nf) { acc##nf[0]=geluf(acc##nf[0]+bias##nf); acc##nf[1]=geluf(acc##nf[1]+bias##nf); \
                      acc##nf[2]=geluf(acc##nf[2]+bias##nf); acc##nf[3]=geluf(acc##nf[3]+bias##nf); }
#define G1_OUT(nf) { const int col = wc*256 + (nf)*16 + l16; \
    const float g_ = lng[col], b_ = lnb[col]; \
    hp[0*H2 + col] = __float2bfloat16((acc##nf[0]-mu0)*rs0*g_ + b_); \
    hp[1*H2 + col] = __float2bfloat16((acc##nf[1]-mu1)*rs1*g_ + b_); \
    hp[2*H2 + col] = __float2bfloat16((acc##nf[2]-mu2)*rs2*g_ + b_); \
    hp[3*H2 + col] = __float2bfloat16((acc##nf[3]-mu3)*rs3*g_ + b_); }

__global__ __launch_bounds__(512) __attribute__((amdgpu_waves_per_eu(1, 4)))
void gemm1_kernel(const __hip_bfloat16* __restrict__ feats,
                  const __hip_bfloat16* __restrict__ w1T,
                  const float* __restrict__ b1,
                  const float* __restrict__ lng,
                  const float* __restrict__ lnb,
                  __hip_bfloat16* __restrict__ h1) {
    __shared__ float lnpart[2][64][2];
    __shared__ float lnstat[64][2];
    const int tid  = threadIdx.x;
    const int wave = tid >> 6;
    const int lane = tid & 63;
    const int quad = lane >> 4;
    const int l16  = lane & 15;
    const int wr   = wave >> 1;     // 0..3: rows wr*16 .. wr*16+15
    const int wc   = wave & 1;      // 0..1: cols wc*256 .. +255
    const int m0   = blockIdx.x * 64;

    const __hip_bfloat16* arow = feats + (size_t)(m0 + wr*16 + l16) * KPAD + quad*8;
    const __hip_bfloat16* brow = w1T   + (size_t)(wc*256 + l16) * KPAD + quad*8;

    REP16(G1_DECL)
#pragma unroll 1
    for (int kt = 0; kt < 9; ++kt) {
        const int ko = kt * 32;
        const short8 av = *(const short8*)(arow + ko);
        REP16(G1_LD)
        REP16(G1_FM)
    }

    REP16(G1_BIAS)
    REP16(G1_GELU)

    // LayerNorm: in-lane sum over 16 nf, shfl over 16 cols, LDS combine halves
    f32x4 s = acc0+acc1+acc2+acc3+acc4+acc5+acc6+acc7+acc8+acc9+acc10+acc11+acc12+acc13+acc14+acc15;
    f32x4 q = acc0*acc0+acc1*acc1+acc2*acc2+acc3*acc3+acc4*acc4+acc5*acc5+acc6*acc6+acc7*acc7
            + acc8*acc8+acc9*acc9+acc10*acc10+acc11*acc11+acc12*acc12+acc13*acc13+acc14*acc14+acc15*acc15;
    s += shfl4(s,1); q += shfl4(q,1);
    s += shfl4(s,2); q += shfl4(q,2);
    s += shfl4(s,4); q += shfl4(q,4);
    s += shfl4(s,8); q += shfl4(q,8);
    if (l16 == 0) {
#pragma unroll
        for (int r = 0; r < 4; ++r) {
            lnpart[wc][wr*16 + quad*4 + r][0] = s[r];
            lnpart[wc][wr*16 + quad*4 + r][1] = q[r];
        }
    }
    __syncthreads();
    if (tid < 64) {
        const float su = lnpart[0][tid][0] + lnpart[1][tid][0];
        const float qu = lnpart[0][tid][1] + lnpart[1][tid][1];
        const float mu  = su * (1.0f / 512.0f);
        const float var = qu * (1.0f / 512.0f) - mu * mu;
        lnstat[tid][0] = mu;
        lnstat[tid][1] = rsqrtf(var + 1e-5f);
    }
    __syncthreads();
    const int rb = wr*16 + quad*4;
    const float mu0 = lnstat[rb+0][0], rs0 = lnstat[rb+0][1];
    const float mu1 = lnstat[rb+1][0], rs1 = lnstat[rb+1][1];
    const float mu2 = lnstat[rb+2][0], rs2 = lnstat[rb+2][1];
    const float mu3 = lnstat[rb+3][0], rs3 = lnstat[rb+3][1];
    __hip_bfloat16* hp = h1 + (size_t)(m0 + rb) * H2;
    REP16(G1_OUT)
}

// ============================================================================
// GEMM2 (direct-load, barrier-free): out = h1 @ w2T + b2 (fp32).
// block = 32 rows x 256 cols, 256 thr = 4 waves as 2(M) x 2(N-half), K=512.
// ============================================================================
#define G2_DECL(nf) f32x4 acc##nf = {0.f,0.f,0.f,0.f};
#define G2_LD(nf)   const short8 bv##nf = *(const short8*)(brow + (nf)*16*H2 + ko);
#define G2_FM(nf)   acc##nf = MFMA(av, bv##nf, acc##nf);
#define G2_OUT(nf) { const int col = wc*128 + (nf)*16 + l16; \
    const float b_ = b2[col]; \
    op[0*HID + col] = acc##nf[0] + b_; \
    op[1*HID + col] = acc##nf[1] + b_; \
    op[2*HID + col] = acc##nf[2] + b_; \
    op[3*HID + col] = acc##nf[3] + b_; }

__global__ __launch_bounds__(256) __attribute__((amdgpu_waves_per_eu(1, 4)))
void gemm2_kernel(const __hip_bfloat16* __restrict__ h1,
                  const __hip_bfloat16* __restrict__ w2T,
                  const float* __restrict__ b2,
                  float* __restrict__ out) {
    const int tid  = threadIdx.x;
    const int wave = tid >> 6;
    const int lane = tid & 63;
    const int quad = lane >> 4;
    const int l16  = lane & 15;
    const int wr   = wave >> 1;     // 0..1: rows wr*16 ..
    const int wc   = wave & 1;      // 0..1: cols wc*128 ..
    const int m0   = blockIdx.x * 32;

    const __hip_bfloat16* arow = h1  + (size_t)(m0 + wr*16 + l16) * H2 + quad*8;
    const __hip_bfloat16* brow = w2T + (size_t)(wc*128 + l16) * H2 + quad*8;

    REP8(G2_DECL)
#pragma unroll 1
    for (int kt = 0; kt < 16; ++kt) {
        const int ko = kt * 32;
        const short8 av = *(const short8*)(arow + ko);
        REP8(G2_LD)
        REP8(G2_FM)
    }
    float* op = out + (size_t)(m0 + wr*16 + quad*4) * HID;
    REP8(G2_OUT)
}

// ============================================================================
extern "C" void kernel_launch(void* const* d_in, const int* in_sizes, int n_in,
                              void* d_out, int out_size, void* d_ws, size_t ws_size,
                              hipStream_t stream) {
    const float* x   = (const float*)d_in[0];
    const float* w1  = (const float*)d_in[1];
    const float* b1  = (const float*)d_in[2];
    const float* lng = (const float*)d_in[3];
    const float* lnb = (const float*)d_in[4];
    const float* w2  = (const float*)d_in[5];
    const float* b2  = (const float*)d_in[6];
    float* out = (float*)d_out;

    char* ws = (char*)d_ws;
    __hip_bfloat16* feats = (__hip_bfloat16*)(ws);                        // 9437184
    __hip_bfloat16* h1    = (__hip_bfloat16*)(ws + 9437184);              // 16777216
    __hip_bfloat16* w1T   = (__hip_bfloat16*)(ws + 26214400);             // 294912
    __hip_bfloat16* w2T   = (__hip_bfloat16*)(ws + 26509312);             // 262144

    convert_w1<<<dim3(512), dim3(288), 0, stream>>>(w1, w1T);
    convert_w2<<<dim3(256), dim3(512), 0, stream>>>(w2, w2T);
    sig_kernel<<<dim3(8 * SBLK), dim3(192), 0, stream>>>(x, feats);
    gemm1_kernel<<<dim3(16384 / 64), dim3(512), 0, stream>>>(feats, w1T, b1, lng, lnb, h1);
    gemm2_kernel<<<dim3(16384 / 32), dim3(256), 0, stream>>>(h1, w2T, b2, out);
}

// Round 9
// 167.090 us; speedup vs baseline: 1.2253x; 1.2253x over previous
//
#include <hip/hip_runtime.h>
#include <hip/hip_bf16.h>
#include <cstdint>
#include <cstddef>

typedef short short8 __attribute__((ext_vector_type(8)));
typedef float f32x4 __attribute__((ext_vector_type(4)));
typedef float f32x2 __attribute__((ext_vector_type(2)));

#define NS    2048
#define KPAD  288
#define H2    512
#define HID   256
#define WPB   7       // windows per sig workgroup (192 thr = 3 waves = 3 thirds)
#define SBLK  293     // ceil(2048/7)
#define KLDS1 296     // 288 padded: stride 148 dw = 20 mod 32 -> 2-way (free)
#define KLDS2 520     // 512 padded: stride 260 dw =  4 mod 32 -> 2-way (free)

#define MFMA(a,b,c) __builtin_amdgcn_mfma_f32_16x16x32_bf16((a),(b),(c),0,0,0)

__device__ __forceinline__ float geluf(float x) {
    return 0.5f * x * (1.0f + erff(x * 0.70710678118654752f));
}
__device__ __forceinline__ f32x4 shfl4(f32x4 v, int d) {
    f32x4 r;
    r[0] = __shfl_xor(v[0], d); r[1] = __shfl_xor(v[1], d);
    r[2] = __shfl_xor(v[2], d); r[3] = __shfl_xor(v[3], d);
    return r;
}

struct Tbl3 { short col[729]; };
static constexpr Tbl3 make_tbl3() {
    Tbl3 t{};
    for (int x = 0; x < 729; ++x) t.col[x] = -1;
    int r = 0;
    for (int i = 0; i < 9; ++i)
        for (int j = 0; j < 9; ++j)
            for (int k = 0; k < 9; ++k) {
                bool lt1 = (i < j) || (i == j && (j < k || (j == k && k < i)));
                bool lt2 = (i < k) || (i == k && (j < i || (j == i && k < j)));
                if (lt1 && lt2) { t.col[(i*9+j)*9+k] = (short)(45 + r); ++r; }
            }
    return t;
}
static constexpr Tbl3 TBL3 = make_tbl3();

// ============================================================================
// sig kernel: UNCHANGED from r7/r8 (3 thirds x 1 wave, pk-f32 math,
// zero-padded diff rows).  <62us; becomes top dispatch; attack next round.
// ============================================================================
#define SIG_STEP(VA_,VB_,VC_) { \
    const float hh = 0.5f * S1i + vi * (1.0f/6.0f); \
    const float ra = S2ra + hh * (VA_); \
    const float rb = S2rb + hh * (VB_); \
    const float rc = S2rc + hh * (VC_); \
    const f32x2 ra2 = {ra, ra}, rb2 = {rb, rb}, rc2 = {rc, rc}; \
    S3sa += ra * v0; S3pa0 += ra2*vp0; S3pa1 += ra2*vp1; S3pa2 += ra2*vp2; S3pa3 += ra2*vp3; \
    S3sb += rb * v0; S3pb0 += rb2*vp0; S3pb1 += rb2*vp1; S3pb2 += rb2*vp2; S3pb3 += rb2*vp3; \
    S3sc += rc * v0; S3pc0 += rc2*vp0; S3pc1 += rc2*vp1; S3pc2 += rc2*vp2; S3pc3 += rc2*vp3; \
    const float aa = S1i + 0.5f * vi; \
    S2ra += aa * (VA_); S2rb += aa * (VB_); S2rc += aa * (VC_); \
    S1i += vi; }

#define SIG_MAIN(VA_,VB_,VC_) { \
    { const float* xr = &X[(g0 - lo) * 8]; \
      const float4 e0 = *(const float4*)xr; \
      const float4 e1 = *(const float4*)(xr + 4); \
      const float rs = xr[ioff]; \
      const float v0 = 0.0f; \
      const f32x2 vp0 = {e0.x, e0.y}, vp1 = {e0.z, e0.w}, vp2 = {e1.x, e1.y}, vp3 = {e1.z, e1.w}; \
      const float vi = (ci == 0) ? 0.0f : rs; \
      SIG_STEP(VA_,VB_,VC_) } \
    const float* pd = &PD[(sm59 + 1 - lo + 59) * 8]; \
    float4 d0 = *(const float4*)pd; \
    float4 d1 = *(const float4*)(pd + 4); \
    float rn = pd[ioff]; \
    _Pragma("unroll 2") \
    for (int j = 1; j < 60; ++j) { \
      const float4 e0 = d0; const float4 e1 = d1; const float rs = rn; \
      pd += 8; \
      d0 = *(const float4*)pd; d1 = *(const float4*)(pd + 4); rn = pd[ioff]; \
      const float v0 = DT; \
      const f32x2 vp0 = {e0.x, e0.y}, vp1 = {e0.z, e0.w}, vp2 = {e1.x, e1.y}, vp3 = {e1.z, e1.w}; \
      const float vi = (ci == 0) ? DT : rs; \
      SIG_STEP(VA_,VB_,VC_) \
    } }

#define SIG_ST(RA,RB,RC) \
    if (act) { \
        if ((RA) == 0) S1buf[widx * 9 + ci] = S1i; \
        float* sb = &S2buf[widx * 81 + ci * 9]; \
        sb[RA] = S2ra; sb[RB] = S2rb; sb[RC] = S2rc; \
    }

#define S3EL0(SL) S3s##SL
#define S3EL1(SL) S3p##SL##0[0]
#define S3EL2(SL) S3p##SL##0[1]
#define S3EL3(SL) S3p##SL##1[0]
#define S3EL4(SL) S3p##SL##1[1]
#define S3EL5(SL) S3p##SL##2[0]
#define S3EL6(SL) S3p##SL##2[1]
#define S3EL7(SL) S3p##SL##3[0]
#define S3EL8(SL) S3p##SL##3[1]

#define SIG_E2(SL,J2) if (ci < (J2)) { \
    const float val2 = S2r##SL - 0.5f * S1i * s1v##J2; \
    const int col2 = 9 + ci*8 - (ci*(ci-1))/2 + ((J2) - ci - 1); \
    frow[col2] = __float2bfloat16(val2); }

#define SIG_E3(SL,R,K) { const int col3 = TBL3.col[tb + (R)*9 + (K)]; \
    if (col3 >= 0) { \
        const float val3 = S3EL##K(SL) \
            - 0.5f * (S1i * S2w[(R)*9+(K)] + S2r##SL * s1v##K) \
            + S1i * s1v##R * s1v##K * (1.0f/3.0f); \
        frow[col3] = __float2bfloat16(val3); } }

#define SIG_E3R(SL,R) SIG_E3(SL,R,0) SIG_E3(SL,R,1) SIG_E3(SL,R,2) SIG_E3(SL,R,3) \
    SIG_E3(SL,R,4) SIG_E3(SL,R,5) SIG_E3(SL,R,6) SIG_E3(SL,R,7) SIG_E3(SL,R,8)

#define SIG_EMIT(RA,RB,RC) \
    if (act) { \
        if ((RA) == 0) { \
            frow[ci] = __float2bfloat16(S1i); \
            if (ci == 0) { \
                const __hip_bfloat16 z16 = __float2bfloat16(0.0f); \
                frow[285] = z16; frow[286] = z16; frow[287] = z16; \
            } \
        } \
        SIG_E2(a,RA) SIG_E2(b,RB) SIG_E2(c,RC) \
        SIG_E3R(a,RA) SIG_E3R(b,RB) SIG_E3R(c,RC) \
    }

__global__ __launch_bounds__(192) __attribute__((amdgpu_waves_per_eu(1, 6)))
void sig_kernel(const float* __restrict__ x, __hip_bfloat16* __restrict__ feats) {
    __shared__ __align__(16) float X[66 * 8];
    __shared__ __align__(16) float PD[126 * 8];
    __shared__ float S2buf[WPB * 81];
    __shared__ float S1buf[WPB * 9];

    const int blk = blockIdx.x;
    const int b   = blk / SBLK;
    const int s0  = (blk % SBLK) * WPB;
    const int lo  = (s0 - 59 > 0) ? (s0 - 59) : 0;
    const int hi  = (s0 + WPB - 1 < NS - 1) ? (s0 + WPB - 1) : (NS - 1);
    const int nrow = hi - lo + 1;     // <= 66
    const int tid = threadIdx.x;

    {
        const float4* src = (const float4*)(x + ((size_t)b * NS + lo) * 8);
        float4* X4 = (float4*)X;
        const int n4 = nrow * 2;
        for (int t = tid; t < n4; t += 192) X4[t] = src[t];
    }
    __syncthreads();
    {
        const float4* X4 = (const float4*)X;
        float4* PD4 = (float4*)PD;
        for (int t = tid; t < 252; t += 192) {
            const int p = t >> 1;
            const int r = p - 59;
            float4 dv = {0.f, 0.f, 0.f, 0.f};
            if (r > 0 && r < nrow) {
                const float4 a = X4[t - 118], bb = X4[t - 120];
                dv.x = a.x - bb.x; dv.y = a.y - bb.y; dv.z = a.z - bb.z; dv.w = a.w - bb.w;
            }
            PD4[t] = dv;
        }
    }
    __syncthreads();

    const int t3    = tid >> 6;
    const int lt    = tid & 63;
    const int widx0 = lt / 9;
    const int ci    = lt - widx0 * 9;
    const bool act  = (lt < 63) && (s0 + widx0 < NS);
    const int widx  = (widx0 < WPB - 1) ? widx0 : WPB - 1;
    int s = s0 + widx; if (s > NS - 1) s = NS - 1;

    float S3sa=0.f, S3sb=0.f, S3sc=0.f;
    f32x2 S3pa0={0.f,0.f},S3pa1={0.f,0.f},S3pa2={0.f,0.f},S3pa3={0.f,0.f};
    f32x2 S3pb0={0.f,0.f},S3pb1={0.f,0.f},S3pb2={0.f,0.f},S3pb3={0.f,0.f};
    f32x2 S3pc0={0.f,0.f},S3pc1={0.f,0.f},S3pc2={0.f,0.f},S3pc3={0.f,0.f};
    float S2ra=0.f, S2rb=0.f, S2rc=0.f;
    float S1i = 0.f;
    const int ioff = (ci > 0) ? (ci - 1) : 0;
    const int sm59 = s - 59;
    const int g0   = (sm59 > 0) ? sm59 : 0;
    const float DT = 1.0f / 59.0f;

    if (t3 == 0)      { SIG_MAIN(v0,   e0.x, e0.y) }
    else if (t3 == 1) { SIG_MAIN(e0.z, e0.w, e1.x) }
    else              { SIG_MAIN(e1.y, e1.z, e1.w) }

    if (t3 == 0)      { SIG_ST(0,1,2) }
    else if (t3 == 1) { SIG_ST(3,4,5) }
    else              { SIG_ST(6,7,8) }
    __syncthreads();

    const float* s1p = &S1buf[widx * 9];
    const float s1v0=s1p[0], s1v1=s1p[1], s1v2=s1p[2], s1v3=s1p[3], s1v4=s1p[4];
    const float s1v5=s1p[5], s1v6=s1p[6], s1v7=s1p[7], s1v8=s1p[8];
    const float* S2w = &S2buf[widx * 81];
    const int tb = ci * 81;
    __hip_bfloat16* frow = feats + (size_t)(b * NS + s) * KPAD;

    if (t3 == 0)      { SIG_EMIT(0,1,2) }
    else if (t3 == 1) { SIG_EMIT(3,4,5) }
    else              { SIG_EMIT(6,7,8) }
}

// ============================================================================
// Weight prep: w1T[512][288] bf16; w2g[n][k] = g_k*w2[k][n] bf16 (r7-proven),
// gw[n] = sum_k g_k w2[k][n], cvec[n] = sum_k beta_k w2[k][n] + b2[n].
// ============================================================================
__global__ void convert_w1(const float* __restrict__ w1, __hip_bfloat16* __restrict__ w1T) {
    const int n = blockIdx.x;          // 0..511
    const int k = threadIdx.x;         // 0..287
    const float v = (k < 285) ? w1[(size_t)k * H2 + n] : 0.0f;
    w1T[(size_t)n * KPAD + k] = __float2bfloat16(v);
}
__global__ void convert_w2g(const float* __restrict__ w2, const float* __restrict__ lng,
                            const float* __restrict__ lnb, const float* __restrict__ b2,
                            __hip_bfloat16* __restrict__ w2g, float* __restrict__ gw,
                            float* __restrict__ cvec) {
    const int n = blockIdx.x, k = threadIdx.x;
    const float wv = w2[(size_t)k * HID + n];
    const float a = lng[k] * wv;
    const float c = lnb[k] * wv;
    w2g[(size_t)n * H2 + k] = __float2bfloat16(a);
    float ra = a, rc = c;
#pragma unroll
    for (int d = 1; d < 64; d <<= 1) { ra += __shfl_xor(ra, d); rc += __shfl_xor(rc, d); }
    __shared__ float r1[8], r2[8];
    const int wv_ = k >> 6, ln = k & 63;
    if (ln == 0) { r1[wv_] = ra; r2[wv_] = rc; }
    __syncthreads();
    if (k == 0) {
        float sa = 0.f, sc = 0.f;
#pragma unroll
        for (int i = 0; i < 8; ++i) { sa += r1[i]; sc += r2[i]; }
        gw[n] = sa; cvec[n] = sc + b2[n];
    }
}

// ============================================================================
// GEMM1 (B-resident LDS, barrier-once): block = 128 M x 64 N, 256 thr/4 waves,
// wave = 32 M x 64 N (mf2 x nf4).  B-tile 64x296 bf16 = 37.9 KB loaded ONCE;
// K-loop is barrier-free: 2 global A + 4 ds_read_b128 + 8 MFMA per kt.
// Stores raw GELU h1 (bf16) + deterministic per-row partial (sum,sq) into
// stats[row][16] (8 N-block sums | 8 sqs) — LN applied in gemm2 (r7 fold).
// r8 lesson: 17 loads/16 MFMA direct from L2 at 2 waves/SIMD = 2% MfmaUtil.
// ============================================================================
__global__ __launch_bounds__(256) __attribute__((amdgpu_waves_per_eu(1, 4)))
void gemm1_kernel(const __hip_bfloat16* __restrict__ feats,
                  const __hip_bfloat16* __restrict__ w1T,
                  const float* __restrict__ b1,
                  __hip_bfloat16* __restrict__ h1,
                  float* __restrict__ stats) {
    __shared__ __align__(16) __hip_bfloat16 ldsB[64 * KLDS1];   // 37888 B
    const int tid  = threadIdx.x;
    const int wave = tid >> 6;
    const int lane = tid & 63;
    const int quad = lane >> 4;
    const int l16  = lane & 15;
    const int m0   = blockIdx.x * 128 + wave * 32;
    const int n0   = blockIdx.y * 64;
    const int nb   = blockIdx.y;

    for (int c = tid; c < 64 * 36; c += 256) {          // B fill, once
        const int n = c / 36, k8 = c - n * 36;
        *(short8*)(ldsB + n * KLDS1 + k8 * 8) =
            *(const short8*)(w1T + (size_t)(n0 + n) * KPAD + k8 * 8);
    }
    __syncthreads();

    const __hip_bfloat16* a0 = feats + (size_t)(m0 + l16) * KPAD + quad * 8;
    const __hip_bfloat16* a1 = feats + (size_t)(m0 + 16 + l16) * KPAD + quad * 8;
    const __hip_bfloat16* bb = ldsB + l16 * KLDS1 + quad * 8;

    f32x4 acc00={0,0,0,0},acc01={0,0,0,0},acc02={0,0,0,0},acc03={0,0,0,0};
    f32x4 acc10={0,0,0,0},acc11={0,0,0,0},acc12={0,0,0,0},acc13={0,0,0,0};
#pragma unroll 1
    for (int kt = 0; kt < 9; ++kt) {
        const int ko = kt * 32;
        const short8 av0 = *(const short8*)(a0 + ko);
        const short8 av1 = *(const short8*)(a1 + ko);
        const short8 bv0 = *(const short8*)(bb + ko);
        const short8 bv1 = *(const short8*)(bb + 16 * KLDS1 + ko);
        const short8 bv2 = *(const short8*)(bb + 32 * KLDS1 + ko);
        const short8 bv3 = *(const short8*)(bb + 48 * KLDS1 + ko);
        acc00 = MFMA(av0, bv0, acc00); acc01 = MFMA(av0, bv1, acc01);
        acc02 = MFMA(av0, bv2, acc02); acc03 = MFMA(av0, bv3, acc03);
        acc10 = MFMA(av1, bv0, acc10); acc11 = MFMA(av1, bv1, acc11);
        acc12 = MFMA(av1, bv2, acc12); acc13 = MFMA(av1, bv3, acc13);
    }

    // bias + exact GELU (C frag: row = quad*4+r, col = l16)
    const float bias0 = b1[n0 +  0 + l16];
    const float bias1 = b1[n0 + 16 + l16];
    const float bias2 = b1[n0 + 32 + l16];
    const float bias3 = b1[n0 + 48 + l16];
#define G1G(A,B) { A[0]=geluf(A[0]+B); A[1]=geluf(A[1]+B); A[2]=geluf(A[2]+B); A[3]=geluf(A[3]+B); }
    G1G(acc00,bias0) G1G(acc01,bias1) G1G(acc02,bias2) G1G(acc03,bias3)
    G1G(acc10,bias0) G1G(acc11,bias1) G1G(acc12,bias2) G1G(acc13,bias3)
#undef G1G

    // per-row partials over this block's 64 cols
    f32x4 s0 = acc00 + acc01 + acc02 + acc03;
    f32x4 q0 = acc00*acc00 + acc01*acc01 + acc02*acc02 + acc03*acc03;
    f32x4 s1 = acc10 + acc11 + acc12 + acc13;
    f32x4 q1 = acc10*acc10 + acc11*acc11 + acc12*acc12 + acc13*acc13;
    s0 += shfl4(s0,1); q0 += shfl4(q0,1); s1 += shfl4(s1,1); q1 += shfl4(q1,1);
    s0 += shfl4(s0,2); q0 += shfl4(q0,2); s1 += shfl4(s1,2); q1 += shfl4(q1,2);
    s0 += shfl4(s0,4); q0 += shfl4(q0,4); s1 += shfl4(s1,4); q1 += shfl4(q1,4);
    s0 += shfl4(s0,8); q0 += shfl4(q0,8); s1 += shfl4(s1,8); q1 += shfl4(q1,8);
    if (l16 == 0) {
#pragma unroll
        for (int r = 0; r < 4; ++r) {
            const int r0 = m0 + quad * 4 + r;
            stats[r0 * 16 + nb] = s0[r]; stats[r0 * 16 + 8 + nb] = q0[r];
            const int r1 = r0 + 16;
            stats[r1 * 16 + nb] = s1[r]; stats[r1 * 16 + 8 + nb] = q1[r];
        }
    }

    // h1 store (raw GELU, bf16)
    {
        __hip_bfloat16* hp = h1 + (size_t)(m0 + quad * 4) * H2;
        const int c0 = n0 + l16;
#pragma unroll
        for (int r = 0; r < 4; ++r) {
            hp[(size_t)r * H2 + c0     ] = __float2bfloat16(acc00[r]);
            hp[(size_t)r * H2 + c0 + 16] = __float2bfloat16(acc01[r]);
            hp[(size_t)r * H2 + c0 + 32] = __float2bfloat16(acc02[r]);
            hp[(size_t)r * H2 + c0 + 48] = __float2bfloat16(acc03[r]);
        }
        __hip_bfloat16* hp2 = hp + (size_t)16 * H2;
#pragma unroll
        for (int r = 0; r < 4; ++r) {
            hp2[(size_t)r * H2 + c0     ] = __float2bfloat16(acc10[r]);
            hp2[(size_t)r * H2 + c0 + 16] = __float2bfloat16(acc11[r]);
            hp2[(size_t)r * H2 + c0 + 32] = __float2bfloat16(acc12[r]);
            hp2[(size_t)r * H2 + c0 + 48] = __float2bfloat16(acc13[r]);
        }
    }
}

// ============================================================================
// GEMM2 (B-resident LDS, barrier-once, LN folded): block = 128 M x 32 N,
// 256 thr/4 waves, wave = 32 M x 32 N (mf2 x nf2).  B-tile 32x520 bf16 =
// 33.3 KB loaded once; per kt: 2 global A + 2 ds + 4 MFMA.
// out = rsv_m*(h1 @ w2g - mu_m*gw[n]) + cvec[n]  (mu/rsv from stats partials)
// ============================================================================
__global__ __launch_bounds__(256) __attribute__((amdgpu_waves_per_eu(1, 4)))
void gemm2_kernel(const __hip_bfloat16* __restrict__ h1,
                  const __hip_bfloat16* __restrict__ w2g,
                  const float* __restrict__ stats,
                  const float* __restrict__ gw,
                  const float* __restrict__ cvec,
                  float* __restrict__ out) {
    __shared__ __align__(16) __hip_bfloat16 ldsB[32 * KLDS2];   // 33280 B
    const int tid  = threadIdx.x;
    const int wave = tid >> 6;
    const int lane = tid & 63;
    const int quad = lane >> 4;
    const int l16  = lane & 15;
    const int m0   = blockIdx.x * 128 + wave * 32;
    const int n0   = blockIdx.y * 32;

    for (int c = tid; c < 32 * 64; c += 256) {          // B fill, once
        const int n = c >> 6, k8 = c & 63;
        *(short8*)(ldsB + n * KLDS2 + k8 * 8) =
            *(const short8*)(w2g + (size_t)(n0 + n) * H2 + k8 * 8);
    }
    __syncthreads();

    const __hip_bfloat16* a0 = h1 + (size_t)(m0 + l16) * H2 + quad * 8;
    const __hip_bfloat16* a1 = h1 + (size_t)(m0 + 16 + l16) * H2 + quad * 8;
    const __hip_bfloat16* bb = ldsB + l16 * KLDS2 + quad * 8;

    f32x4 acc00={0,0,0,0},acc01={0,0,0,0},acc10={0,0,0,0},acc11={0,0,0,0};
#pragma unroll 1
    for (int kt = 0; kt < 16; ++kt) {
        const int ko = kt * 32;
        const short8 av0 = *(const short8*)(a0 + ko);
        const short8 av1 = *(const short8*)(a1 + ko);
        const short8 bv0 = *(const short8*)(bb + ko);
        const short8 bv1 = *(const short8*)(bb + 16 * KLDS2 + ko);
        acc00 = MFMA(av0, bv0, acc00); acc01 = MFMA(av0, bv1, acc01);
        acc10 = MFMA(av1, bv0, acc10); acc11 = MFMA(av1, bv1, acc11);
    }

    const int c0 = n0 + l16, c1 = c0 + 16;
    const float gw0 = gw[c0], gw1 = gw[c1];
    const float cv0 = cvec[c0], cv1 = cvec[c1];
#define G2EP(mf) { \
    const int rbase = m0 + (mf)*16 + quad*4; \
    _Pragma("unroll") \
    for (int r = 0; r < 4; ++r) { \
        const int row = rbase + r; \
        const float4 sA = *(const float4*)&stats[row*16]; \
        const float4 sB = *(const float4*)&stats[row*16+4]; \
        const float4 qA = *(const float4*)&stats[row*16+8]; \
        const float4 qB = *(const float4*)&stats[row*16+12]; \
        const float su = sA.x+sA.y+sA.z+sA.w + sB.x+sB.y+sB.z+sB.w; \
        const float qu = qA.x+qA.y+qA.z+qA.w + qB.x+qB.y+qB.z+qB.w; \
        const float mu = su * (1.0f/512.0f); \
        const float rsv = rsqrtf(qu*(1.0f/512.0f) - mu*mu + 1e-5f); \
        out[(size_t)row*HID + c0] = rsv*(acc##mf##0[r] - mu*gw0) + cv0; \
        out[(size_t)row*HID + c1] = rsv*(acc##mf##1[r] - mu*gw1) + cv1; \
    } }
    G2EP(0) G2EP(1)
#undef G2EP
}

// ============================================================================
extern "C" void kernel_launch(void* const* d_in, const int* in_sizes, int n_in,
                              void* d_out, int out_size, void* d_ws, size_t ws_size,
                              hipStream_t stream) {
    const float* x   = (const float*)d_in[0];
    const float* w1  = (const float*)d_in[1];
    const float* b1  = (const float*)d_in[2];
    const float* lng = (const float*)d_in[3];
    const float* lnb = (const float*)d_in[4];
    const float* w2  = (const float*)d_in[5];
    const float* b2  = (const float*)d_in[6];
    float* out = (float*)d_out;

    char* ws = (char*)d_ws;
    __hip_bfloat16* feats = (__hip_bfloat16*)(ws);                        // 9437184
    __hip_bfloat16* h1    = (__hip_bfloat16*)(ws + 9437184);              // 16777216
    __hip_bfloat16* w1T   = (__hip_bfloat16*)(ws + 26214400);             // 294912
    __hip_bfloat16* w2g   = (__hip_bfloat16*)(ws + 26509312);             // 262144
    float*          gw    = (float*)(ws + 26771456);                      // 4096
    float*          cvec  = (float*)(ws + 26775552);                      // 4096
    float*          stats = (float*)(ws + 26779648);                      // 16384*16*4 = 1048576

    convert_w1<<<dim3(512), dim3(288), 0, stream>>>(w1, w1T);
    convert_w2g<<<dim3(256), dim3(512), 0, stream>>>(w2, lng, lnb, b2, w2g, gw, cvec);
    sig_kernel<<<dim3(8 * SBLK), dim3(192), 0, stream>>>(x, feats);
    gemm1_kernel<<<dim3(128, 8), dim3(256), 0, stream>>>(feats, w1T, b1, h1, stats);
    gemm2_kernel<<<dim3(128, 8), dim3(256), 0, stream>>>(h1, w2g, stats, gw, cvec, out);
}

// Round 10
// 164.794 us; speedup vs baseline: 1.2424x; 1.0139x over previous
//
#include <hip/hip_runtime.h>
#include <hip/hip_bf16.h>
#include <cstdint>
#include <cstddef>

typedef short short8 __attribute__((ext_vector_type(8)));
typedef float f32x4 __attribute__((ext_vector_type(4)));
typedef float f32x2 __attribute__((ext_vector_type(2)));

#define NS    2048
#define KPAD  288
#define H2    512
#define HID   256
#define WPB   7       // windows per sig workgroup (192 thr = 3 waves = 3 thirds)
#define SBLK  293     // ceil(2048/7)
#define KLDS1 296     // 288 padded: stride 148 dw = 20 mod 32 -> 2-way (free)
#define KLDS2 520     // 512 padded: stride 260 dw =  4 mod 32 -> 2-way (free)

#define MFMA(a,b,c) __builtin_amdgcn_mfma_f32_16x16x32_bf16((a),(b),(c),0,0,0)

__device__ __forceinline__ float geluf(float x) {
    return 0.5f * x * (1.0f + erff(x * 0.70710678118654752f));
}
__device__ __forceinline__ f32x4 shfl4(f32x4 v, int d) {
    f32x4 r;
    r[0] = __shfl_xor(v[0], d); r[1] = __shfl_xor(v[1], d);
    r[2] = __shfl_xor(v[2], d); r[3] = __shfl_xor(v[3], d);
    return r;
}

struct Tbl3 { short col[729]; };
static constexpr Tbl3 make_tbl3() {
    Tbl3 t{};
    for (int x = 0; x < 729; ++x) t.col[x] = -1;
    int r = 0;
    for (int i = 0; i < 9; ++i)
        for (int j = 0; j < 9; ++j)
            for (int k = 0; k < 9; ++k) {
                bool lt1 = (i < j) || (i == j && (j < k || (j == k && k < i)));
                bool lt2 = (i < k) || (i == k && (j < i || (j == i && k < j)));
                if (lt1 && lt2) { t.col[(i*9+j)*9+k] = (short)(45 + r); ++r; }
            }
    return t;
}
static constexpr Tbl3 TBL3 = make_tbl3();

// ============================================================================
// sig kernel (r9 + unroll 4): VALU-issue ~24us and LDS-pipe ~24us measured as
// the SUM (47.8us) -> pipes not overlapping.  unroll 4 puts 4 independent
// prefetch rows in flight per body (~480 inst/path ~ 8KB, I$-safe).
// ============================================================================
#define SIG_STEP(VA_,VB_,VC_) { \
    const float hh = 0.5f * S1i + vi * (1.0f/6.0f); \
    const float ra = S2ra + hh * (VA_); \
    const float rb = S2rb + hh * (VB_); \
    const float rc = S2rc + hh * (VC_); \
    const f32x2 ra2 = {ra, ra}, rb2 = {rb, rb}, rc2 = {rc, rc}; \
    S3sa += ra * v0; S3pa0 += ra2*vp0; S3pa1 += ra2*vp1; S3pa2 += ra2*vp2; S3pa3 += ra2*vp3; \
    S3sb += rb * v0; S3pb0 += rb2*vp0; S3pb1 += rb2*vp1; S3pb2 += rb2*vp2; S3pb3 += rb2*vp3; \
    S3sc += rc * v0; S3pc0 += rc2*vp0; S3pc1 += rc2*vp1; S3pc2 += rc2*vp2; S3pc3 += rc2*vp3; \
    const float aa = S1i + 0.5f * vi; \
    S2ra += aa * (VA_); S2rb += aa * (VB_); S2rc += aa * (VC_); \
    S1i += vi; }

#define SIG_MAIN(VA_,VB_,VC_) { \
    { const float* xr = &X[(g0 - lo) * 8]; \
      const float4 e0 = *(const float4*)xr; \
      const float4 e1 = *(const float4*)(xr + 4); \
      const float rs = xr[ioff]; \
      const float v0 = 0.0f; \
      const f32x2 vp0 = {e0.x, e0.y}, vp1 = {e0.z, e0.w}, vp2 = {e1.x, e1.y}, vp3 = {e1.z, e1.w}; \
      const float vi = (ci == 0) ? 0.0f : rs; \
      SIG_STEP(VA_,VB_,VC_) } \
    const float* pd = &PD[(sm59 + 1 - lo + 59) * 8]; \
    float4 d0 = *(const float4*)pd; \
    float4 d1 = *(const float4*)(pd + 4); \
    float rn = pd[ioff]; \
    _Pragma("unroll 4") \
    for (int j = 1; j < 60; ++j) { \
      const float4 e0 = d0; const float4 e1 = d1; const float rs = rn; \
      pd += 8; \
      d0 = *(const float4*)pd; d1 = *(const float4*)(pd + 4); rn = pd[ioff]; \
      const float v0 = DT; \
      const f32x2 vp0 = {e0.x, e0.y}, vp1 = {e0.z, e0.w}, vp2 = {e1.x, e1.y}, vp3 = {e1.z, e1.w}; \
      const float vi = (ci == 0) ? DT : rs; \
      SIG_STEP(VA_,VB_,VC_) \
    } }

#define SIG_ST(RA,RB,RC) \
    if (act) { \
        if ((RA) == 0) S1buf[widx * 9 + ci] = S1i; \
        float* sb = &S2buf[widx * 81 + ci * 9]; \
        sb[RA] = S2ra; sb[RB] = S2rb; sb[RC] = S2rc; \
    }

#define S3EL0(SL) S3s##SL
#define S3EL1(SL) S3p##SL##0[0]
#define S3EL2(SL) S3p##SL##0[1]
#define S3EL3(SL) S3p##SL##1[0]
#define S3EL4(SL) S3p##SL##1[1]
#define S3EL5(SL) S3p##SL##2[0]
#define S3EL6(SL) S3p##SL##2[1]
#define S3EL7(SL) S3p##SL##3[0]
#define S3EL8(SL) S3p##SL##3[1]

#define SIG_E2(SL,J2) if (ci < (J2)) { \
    const float val2 = S2r##SL - 0.5f * S1i * s1v##J2; \
    const int col2 = 9 + ci*8 - (ci*(ci-1))/2 + ((J2) - ci - 1); \
    frow[col2] = __float2bfloat16(val2); }

#define SIG_E3(SL,R,K) { const int col3 = TBL3.col[tb + (R)*9 + (K)]; \
    if (col3 >= 0) { \
        const float val3 = S3EL##K(SL) \
            - 0.5f * (S1i * S2w[(R)*9+(K)] + S2r##SL * s1v##K) \
            + S1i * s1v##R * s1v##K * (1.0f/3.0f); \
        frow[col3] = __float2bfloat16(val3); } }

#define SIG_E3R(SL,R) SIG_E3(SL,R,0) SIG_E3(SL,R,1) SIG_E3(SL,R,2) SIG_E3(SL,R,3) \
    SIG_E3(SL,R,4) SIG_E3(SL,R,5) SIG_E3(SL,R,6) SIG_E3(SL,R,7) SIG_E3(SL,R,8)

#define SIG_EMIT(RA,RB,RC) \
    if (act) { \
        if ((RA) == 0) { \
            frow[ci] = __float2bfloat16(S1i); \
            if (ci == 0) { \
                const __hip_bfloat16 z16 = __float2bfloat16(0.0f); \
                frow[285] = z16; frow[286] = z16; frow[287] = z16; \
            } \
        } \
        SIG_E2(a,RA) SIG_E2(b,RB) SIG_E2(c,RC) \
        SIG_E3R(a,RA) SIG_E3R(b,RB) SIG_E3R(c,RC) \
    }

__global__ __launch_bounds__(192) __attribute__((amdgpu_waves_per_eu(1, 6)))
void sig_kernel(const float* __restrict__ x, __hip_bfloat16* __restrict__ feats) {
    __shared__ __align__(16) float X[66 * 8];
    __shared__ __align__(16) float PD[126 * 8];
    __shared__ float S2buf[WPB * 81];
    __shared__ float S1buf[WPB * 9];

    const int blk = blockIdx.x;
    const int b   = blk / SBLK;
    const int s0  = (blk % SBLK) * WPB;
    const int lo  = (s0 - 59 > 0) ? (s0 - 59) : 0;
    const int hi  = (s0 + WPB - 1 < NS - 1) ? (s0 + WPB - 1) : (NS - 1);
    const int nrow = hi - lo + 1;     // <= 66
    const int tid = threadIdx.x;

    {
        const float4* src = (const float4*)(x + ((size_t)b * NS + lo) * 8);
        float4* X4 = (float4*)X;
        const int n4 = nrow * 2;
        for (int t = tid; t < n4; t += 192) X4[t] = src[t];
    }
    __syncthreads();
    {
        const float4* X4 = (const float4*)X;
        float4* PD4 = (float4*)PD;
        for (int t = tid; t < 252; t += 192) {
            const int p = t >> 1;
            const int r = p - 59;
            float4 dv = {0.f, 0.f, 0.f, 0.f};
            if (r > 0 && r < nrow) {
                const float4 a = X4[t - 118], bb = X4[t - 120];
                dv.x = a.x - bb.x; dv.y = a.y - bb.y; dv.z = a.z - bb.z; dv.w = a.w - bb.w;
            }
            PD4[t] = dv;
        }
    }
    __syncthreads();

    const int t3    = tid >> 6;
    const int lt    = tid & 63;
    const int widx0 = lt / 9;
    const int ci    = lt - widx0 * 9;
    const bool act  = (lt < 63) && (s0 + widx0 < NS);
    const int widx  = (widx0 < WPB - 1) ? widx0 : WPB - 1;
    int s = s0 + widx; if (s > NS - 1) s = NS - 1;

    float S3sa=0.f, S3sb=0.f, S3sc=0.f;
    f32x2 S3pa0={0.f,0.f},S3pa1={0.f,0.f},S3pa2={0.f,0.f},S3pa3={0.f,0.f};
    f32x2 S3pb0={0.f,0.f},S3pb1={0.f,0.f},S3pb2={0.f,0.f},S3pb3={0.f,0.f};
    f32x2 S3pc0={0.f,0.f},S3pc1={0.f,0.f},S3pc2={0.f,0.f},S3pc3={0.f,0.f};
    float S2ra=0.f, S2rb=0.f, S2rc=0.f;
    float S1i = 0.f;
    const int ioff = (ci > 0) ? (ci - 1) : 0;
    const int sm59 = s - 59;
    const int g0   = (sm59 > 0) ? sm59 : 0;
    const float DT = 1.0f / 59.0f;

    if (t3 == 0)      { SIG_MAIN(v0,   e0.x, e0.y) }
    else if (t3 == 1) { SIG_MAIN(e0.z, e0.w, e1.x) }
    else              { SIG_MAIN(e1.y, e1.z, e1.w) }

    if (t3 == 0)      { SIG_ST(0,1,2) }
    else if (t3 == 1) { SIG_ST(3,4,5) }
    else              { SIG_ST(6,7,8) }
    __syncthreads();

    const float* s1p = &S1buf[widx * 9];
    const float s1v0=s1p[0], s1v1=s1p[1], s1v2=s1p[2], s1v3=s1p[3], s1v4=s1p[4];
    const float s1v5=s1p[5], s1v6=s1p[6], s1v7=s1p[7], s1v8=s1p[8];
    const float* S2w = &S2buf[widx * 81];
    const int tb = ci * 81;
    __hip_bfloat16* frow = feats + (size_t)(b * NS + s) * KPAD;

    if (t3 == 0)      { SIG_EMIT(0,1,2) }
    else if (t3 == 1) { SIG_EMIT(3,4,5) }
    else              { SIG_EMIT(6,7,8) }
}

// ============================================================================
// Fused weight prep (one launch): blocks 0..511 -> w1T; 512..767 -> w2g/gw/cvec
// ============================================================================
__global__ __launch_bounds__(512) void convert_weights(
        const float* __restrict__ w1, const float* __restrict__ w2,
        const float* __restrict__ lng, const float* __restrict__ lnb,
        const float* __restrict__ b2,
        __hip_bfloat16* __restrict__ w1T, __hip_bfloat16* __restrict__ w2g,
        float* __restrict__ gw, float* __restrict__ cvec) {
    const int blk = blockIdx.x;
    const int k = threadIdx.x;
    if (blk < 512) {
        if (k < KPAD) {
            const float v = (k < 285) ? w1[(size_t)k * H2 + blk] : 0.0f;
            w1T[(size_t)blk * KPAD + k] = __float2bfloat16(v);
        }
        return;
    }
    const int n = blk - 512;           // 0..255
    const float wv = w2[(size_t)k * HID + n];
    const float a = lng[k] * wv;
    const float c = lnb[k] * wv;
    w2g[(size_t)n * H2 + k] = __float2bfloat16(a);
    float ra = a, rc = c;
#pragma unroll
    for (int d = 1; d < 64; d <<= 1) { ra += __shfl_xor(ra, d); rc += __shfl_xor(rc, d); }
    __shared__ float r1[8], r2[8];
    const int wv_ = k >> 6, ln = k & 63;
    if (ln == 0) { r1[wv_] = ra; r2[wv_] = rc; }
    __syncthreads();
    if (k == 0) {
        float sa = 0.f, sc = 0.f;
#pragma unroll
        for (int i = 0; i < 8; ++i) { sa += r1[i]; sc += r2[i]; }
        gw[n] = sa; cvec[n] = sc + b2[n];
    }
}

// ============================================================================
// GEMM1 (B-resident LDS, barrier-once, FULLY-UNROLLED K-loop): r9's unroll-1
// K-loop serialized 9 dependent global-load latencies per wave; full unroll
// lets the compiler hoist all 18 A-loads early with staggered vmcnt waits.
// block = 128M x 64N, 256 thr/4 waves, wave = 32M x 64N.
// ============================================================================
__global__ __launch_bounds__(256) __attribute__((amdgpu_waves_per_eu(1, 4)))
void gemm1_kernel(const __hip_bfloat16* __restrict__ feats,
                  const __hip_bfloat16* __restrict__ w1T,
                  const float* __restrict__ b1,
                  __hip_bfloat16* __restrict__ h1,
                  float* __restrict__ stats) {
    __shared__ __align__(16) __hip_bfloat16 ldsB[64 * KLDS1];   // 37888 B
    const int tid  = threadIdx.x;
    const int wave = tid >> 6;
    const int lane = tid & 63;
    const int quad = lane >> 4;
    const int l16  = lane & 15;
    const int m0   = blockIdx.x * 128 + wave * 32;
    const int n0   = blockIdx.y * 64;
    const int nb   = blockIdx.y;

    for (int c = tid; c < 64 * 36; c += 256) {          // B fill, once
        const int n = c / 36, k8 = c - n * 36;
        *(short8*)(ldsB + n * KLDS1 + k8 * 8) =
            *(const short8*)(w1T + (size_t)(n0 + n) * KPAD + k8 * 8);
    }
    __syncthreads();

    const __hip_bfloat16* a0 = feats + (size_t)(m0 + l16) * KPAD + quad * 8;
    const __hip_bfloat16* a1 = feats + (size_t)(m0 + 16 + l16) * KPAD + quad * 8;
    const __hip_bfloat16* bb = ldsB + l16 * KLDS1 + quad * 8;

    f32x4 acc00={0,0,0,0},acc01={0,0,0,0},acc02={0,0,0,0},acc03={0,0,0,0};
    f32x4 acc10={0,0,0,0},acc11={0,0,0,0},acc12={0,0,0,0},acc13={0,0,0,0};
#pragma unroll
    for (int kt = 0; kt < 9; ++kt) {
        const int ko = kt * 32;
        const short8 av0 = *(const short8*)(a0 + ko);
        const short8 av1 = *(const short8*)(a1 + ko);
        const short8 bv0 = *(const short8*)(bb + ko);
        const short8 bv1 = *(const short8*)(bb + 16 * KLDS1 + ko);
        const short8 bv2 = *(const short8*)(bb + 32 * KLDS1 + ko);
        const short8 bv3 = *(const short8*)(bb + 48 * KLDS1 + ko);
        acc00 = MFMA(av0, bv0, acc00); acc01 = MFMA(av0, bv1, acc01);
        acc02 = MFMA(av0, bv2, acc02); acc03 = MFMA(av0, bv3, acc03);
        acc10 = MFMA(av1, bv0, acc10); acc11 = MFMA(av1, bv1, acc11);
        acc12 = MFMA(av1, bv2, acc12); acc13 = MFMA(av1, bv3, acc13);
    }

    // bias + exact GELU (C frag: row = quad*4+r, col = l16)
    const float bias0 = b1[n0 +  0 + l16];
    const float bias1 = b1[n0 + 16 + l16];
    const float bias2 = b1[n0 + 32 + l16];
    const float bias3 = b1[n0 + 48 + l16];
#define G1G(A,B) { A[0]=geluf(A[0]+B); A[1]=geluf(A[1]+B); A[2]=geluf(A[2]+B); A[3]=geluf(A[3]+B); }
    G1G(acc00,bias0) G1G(acc01,bias1) G1G(acc02,bias2) G1G(acc03,bias3)
    G1G(acc10,bias0) G1G(acc11,bias1) G1G(acc12,bias2) G1G(acc13,bias3)
#undef G1G

    // per-row partials over this block's 64 cols
    f32x4 s0 = acc00 + acc01 + acc02 + acc03;
    f32x4 q0 = acc00*acc00 + acc01*acc01 + acc02*acc02 + acc03*acc03;
    f32x4 s1 = acc10 + acc11 + acc12 + acc13;
    f32x4 q1 = acc10*acc10 + acc11*acc11 + acc12*acc12 + acc13*acc13;
    s0 += shfl4(s0,1); q0 += shfl4(q0,1); s1 += shfl4(s1,1); q1 += shfl4(q1,1);
    s0 += shfl4(s0,2); q0 += shfl4(q0,2); s1 += shfl4(s1,2); q1 += shfl4(q1,2);
    s0 += shfl4(s0,4); q0 += shfl4(q0,4); s1 += shfl4(s1,4); q1 += shfl4(q1,4);
    s0 += shfl4(s0,8); q0 += shfl4(q0,8); s1 += shfl4(s1,8); q1 += shfl4(q1,8);
    if (l16 == 0) {
#pragma unroll
        for (int r = 0; r < 4; ++r) {
            const int r0 = m0 + quad * 4 + r;
            stats[r0 * 16 + nb] = s0[r]; stats[r0 * 16 + 8 + nb] = q0[r];
            const int r1 = r0 + 16;
            stats[r1 * 16 + nb] = s1[r]; stats[r1 * 16 + 8 + nb] = q1[r];
        }
    }

    // h1 store (raw GELU, bf16)
    {
        __hip_bfloat16* hp = h1 + (size_t)(m0 + quad * 4) * H2;
        const int c0 = n0 + l16;
#pragma unroll
        for (int r = 0; r < 4; ++r) {
            hp[(size_t)r * H2 + c0     ] = __float2bfloat16(acc00[r]);
            hp[(size_t)r * H2 + c0 + 16] = __float2bfloat16(acc01[r]);
            hp[(size_t)r * H2 + c0 + 32] = __float2bfloat16(acc02[r]);
            hp[(size_t)r * H2 + c0 + 48] = __float2bfloat16(acc03[r]);
        }
        __hip_bfloat16* hp2 = hp + (size_t)16 * H2;
#pragma unroll
        for (int r = 0; r < 4; ++r) {
            hp2[(size_t)r * H2 + c0     ] = __float2bfloat16(acc10[r]);
            hp2[(size_t)r * H2 + c0 + 16] = __float2bfloat16(acc11[r]);
            hp2[(size_t)r * H2 + c0 + 32] = __float2bfloat16(acc12[r]);
            hp2[(size_t)r * H2 + c0 + 48] = __float2bfloat16(acc13[r]);
        }
    }
}

// ============================================================================
// GEMM2 (B-resident LDS, barrier-once, FULLY-UNROLLED K-loop, LN folded):
// block = 128M x 32N, 256 thr/4 waves, wave = 32M x 32N, K=512 (16 steps).
// out = rsv_m*(h1 @ w2g - mu_m*gw[n]) + cvec[n]
// ============================================================================
__global__ __launch_bounds__(256) __attribute__((amdgpu_waves_per_eu(1, 4)))
void gemm2_kernel(const __hip_bfloat16* __restrict__ h1,
                  const __hip_bfloat16* __restrict__ w2g,
                  const float* __restrict__ stats,
                  const float* __restrict__ gw,
                  const float* __restrict__ cvec,
                  float* __restrict__ out) {
    __shared__ __align__(16) __hip_bfloat16 ldsB[32 * KLDS2];   // 33280 B
    const int tid  = threadIdx.x;
    const int wave = tid >> 6;
    const int lane = tid & 63;
    const int quad = lane >> 4;
    const int l16  = lane & 15;
    const int m0   = blockIdx.x * 128 + wave * 32;
    const int n0   = blockIdx.y * 32;

    for (int c = tid; c < 32 * 64; c += 256) {          // B fill, once
        const int n = c >> 6, k8 = c & 63;
        *(short8*)(ldsB + n * KLDS2 + k8 * 8) =
            *(const short8*)(w2g + (size_t)(n0 + n) * H2 + k8 * 8);
    }
    __syncthreads();

    const __hip_bfloat16* a0 = h1 + (size_t)(m0 + l16) * H2 + quad * 8;
    const __hip_bfloat16* a1 = h1 + (size_t)(m0 + 16 + l16) * H2 + quad * 8;
    const __hip_bfloat16* bb = ldsB + l16 * KLDS2 + quad * 8;

    f32x4 acc00={0,0,0,0},acc01={0,0,0,0},acc10={0,0,0,0},acc11={0,0,0,0};
#pragma unroll
    for (int kt = 0; kt < 16; ++kt) {
        const int ko = kt * 32;
        const short8 av0 = *(const short8*)(a0 + ko);
        const short8 av1 = *(const short8*)(a1 + ko);
        const short8 bv0 = *(const short8*)(bb + ko);
        const short8 bv1 = *(const short8*)(bb + 16 * KLDS2 + ko);
        acc00 = MFMA(av0, bv0, acc00); acc01 = MFMA(av0, bv1, acc01);
        acc10 = MFMA(av1, bv0, acc10); acc11 = MFMA(av1, bv1, acc11);
    }

    const int c0 = n0 + l16, c1 = c0 + 16;
    const float gw0 = gw[c0], gw1 = gw[c1];
    const float cv0 = cvec[c0], cv1 = cvec[c1];
#define G2EP(mf) { \
    const int rbase = m0 + (mf)*16 + quad*4; \
    _Pragma("unroll") \
    for (int r = 0; r < 4; ++r) { \
        const int row = rbase + r; \
        const float4 sA = *(const float4*)&stats[row*16]; \
        const float4 sB = *(const float4*)&stats[row*16+4]; \
        const float4 qA = *(const float4*)&stats[row*16+8]; \
        const float4 qB = *(const float4*)&stats[row*16+12]; \
        const float su = sA.x+sA.y+sA.z+sA.w + sB.x+sB.y+sB.z+sB.w; \
        const float qu = qA.x+qA.y+qA.z+qA.w + qB.x+qB.y+qB.z+qB.w; \
        const float mu = su * (1.0f/512.0f); \
        const float rsv = rsqrtf(qu*(1.0f/512.0f) - mu*mu + 1e-5f); \
        out[(size_t)row*HID + c0] = rsv*(acc##mf##0[r] - mu*gw0) + cv0; \
        out[(size_t)row*HID + c1] = rsv*(acc##mf##1[r] - mu*gw1) + cv1; \
    } }
    G2EP(0) G2EP(1)
#undef G2EP
}

// ============================================================================
extern "C" void kernel_launch(void* const* d_in, const int* in_sizes, int n_in,
                              void* d_out, int out_size, void* d_ws, size_t ws_size,
                              hipStream_t stream) {
    const float* x   = (const float*)d_in[0];
    const float* w1  = (const float*)d_in[1];
    const float* b1  = (const float*)d_in[2];
    const float* lng = (const float*)d_in[3];
    const float* lnb = (const float*)d_in[4];
    const float* w2  = (const float*)d_in[5];
    const float* b2  = (const float*)d_in[6];
    float* out = (float*)d_out;

    char* ws = (char*)d_ws;
    __hip_bfloat16* feats = (__hip_bfloat16*)(ws);                        // 9437184
    __hip_bfloat16* h1    = (__hip_bfloat16*)(ws + 9437184);              // 16777216
    __hip_bfloat16* w1T   = (__hip_bfloat16*)(ws + 26214400);             // 294912
    __hip_bfloat16* w2g   = (__hip_bfloat16*)(ws + 26509312);             // 262144
    float*          gw    = (float*)(ws + 26771456);                      // 4096
    float*          cvec  = (float*)(ws + 26775552);                      // 4096
    float*          stats = (float*)(ws + 26779648);                      // 16384*16*4 = 1048576

    convert_weights<<<dim3(768), dim3(512), 0, stream>>>(w1, w2, lng, lnb, b2,
                                                         w1T, w2g, gw, cvec);
    sig_kernel<<<dim3(8 * SBLK), dim3(192), 0, stream>>>(x, feats);
    gemm1_kernel<<<dim3(128, 8), dim3(256), 0, stream>>>(feats, w1T, b1, h1, stats);
    gemm2_kernel<<<dim3(128, 8), dim3(256), 0, stream>>>(h1, w2g, stats, gw, cvec, out);
}